// Round 1
// baseline (539.608 us; speedup 1.0000x reference)
//
#include <hip/hip_runtime.h>
#include <math.h>

#define NN 50000
#define NE 800000
#define NTOT (NN + NE)   // 850000 CSR entries (edges + self loops)

// ---------------- CSR build ----------------

__global__ __launch_bounds__(256) void hist_kernel(const int* __restrict__ dst,
                                                   int* __restrict__ cnt) {
    int e = blockIdx.x * 256 + threadIdx.x;
    if (e < NE) atomicAdd(&cnt[dst[e]], 1);
}

// Single-workgroup exclusive scan of (cnt[i]+1) -> row_ptr; also dinv = 1/sqrt(deg).
__global__ __launch_bounds__(1024) void scan_kernel(const int* __restrict__ cnt,
                                                    int* __restrict__ row_ptr,
                                                    float* __restrict__ dinv) {
    const int T = 1024;
    const int per = (NN + T - 1) / T;  // 49
    int lo = threadIdx.x * per;
    int hi = lo + per; if (hi > NN) hi = NN;
    int sum = 0;
    for (int i = lo; i < hi; ++i) {
        int v = cnt[i] + 1;            // +1 self loop
        sum += v;
        dinv[i] = (float)(1.0 / sqrt((double)v));
    }
    __shared__ int tmp[1024];
    tmp[threadIdx.x] = sum;
    __syncthreads();
    for (int s = 1; s < T; s <<= 1) {
        int t = (threadIdx.x >= s) ? tmp[threadIdx.x - s] : 0;
        __syncthreads();
        tmp[threadIdx.x] += t;
        __syncthreads();
    }
    int run = tmp[threadIdx.x] - sum;  // exclusive prefix
    for (int i = lo; i < hi; ++i) {
        int v = cnt[i] + 1;
        row_ptr[i] = run;
        run += v;
    }
    if (threadIdx.x == T - 1) row_ptr[NN] = run;   // = NTOT
}

// Place self loop at row start, init cursor.
__global__ __launch_bounds__(256) void self_kernel(const int* __restrict__ row_ptr,
                                                   const float* __restrict__ dinv,
                                                   int* __restrict__ cursor,
                                                   int* __restrict__ col,
                                                   float* __restrict__ val) {
    int i = blockIdx.x * 256 + threadIdx.x;
    if (i < NN) {
        int p = row_ptr[i];
        col[p] = i;
        float di = dinv[i];
        val[p] = di * di;
        cursor[i] = p + 1;
    }
}

__global__ __launch_bounds__(256) void scatter_kernel(const int* __restrict__ src,
                                                      const int* __restrict__ dst,
                                                      const float* __restrict__ dinv,
                                                      int* __restrict__ cursor,
                                                      int* __restrict__ col,
                                                      float* __restrict__ val) {
    int e = blockIdx.x * 256 + threadIdx.x;
    if (e < NE) {
        int s = src[e], d = dst[e];
        int p = atomicAdd(&cursor[d], 1);
        col[p] = s;
        val[p] = dinv[s] * dinv[d];
    }
}

// ---------------- dense GEMM: out[N x DOUT] = A[N x 128] @ W[128 x DOUT] ----------------
// 256 threads; CG = DOUT/4 col-groups, RT = 256/CG row-threads, RPT rows/thread.
// A tile staged in LDS with pad stride 132 (row->+4 banks, only 2-way aliasing = free).

template <int DOUT, int RPT>
__global__ __launch_bounds__(256) void gemm_kernel(const float* __restrict__ A,
                                                   const float* __restrict__ W,
                                                   float* __restrict__ out) {
    constexpr int CG = DOUT / 4;      // 32 or 16
    constexpr int RT = 256 / CG;      // 8 or 16
    constexpr int ROWS = RT * RPT;    // 64 rows/block
    constexpr int LD = 132;
    __shared__ float lds[ROWS * LD];
    const int t = threadIdx.x;
    const int row0 = blockIdx.x * ROWS;

    // stage A tile (ROWS x 128 fp32), coalesced float4
    #pragma unroll
    for (int j = 0; j < ROWS / 8; ++j) {
        int idx4 = j * 256 + t;              // 0 .. ROWS*32-1
        int r = idx4 >> 5, c4 = idx4 & 31;
        int gr = row0 + r;
        float4 v = make_float4(0.f, 0.f, 0.f, 0.f);
        if (gr < NN) v = ((const float4*)(A + (size_t)gr * 128))[c4];
        ((float4*)(lds + r * LD))[c4] = v;
    }
    __syncthreads();

    const int cg = t % CG;
    const int rt = t / CG;
    const float4* Wv = (const float4*)W;
    float4 acc[RPT];
    #pragma unroll
    for (int i = 0; i < RPT; ++i) acc[i] = make_float4(0.f, 0.f, 0.f, 0.f);

    for (int k0 = 0; k0 < 128; k0 += 4) {
        float4 w0 = Wv[(k0 + 0) * CG + cg];
        float4 w1 = Wv[(k0 + 1) * CG + cg];
        float4 w2 = Wv[(k0 + 2) * CG + cg];
        float4 w3 = Wv[(k0 + 3) * CG + cg];
        #pragma unroll
        for (int i = 0; i < RPT; ++i) {
            const float* lr = lds + (rt * RPT + i) * LD;
            float4 a = ((const float4*)lr)[k0 >> 2];
            acc[i].x += a.x * w0.x + a.y * w1.x + a.z * w2.x + a.w * w3.x;
            acc[i].y += a.x * w0.y + a.y * w1.y + a.z * w2.y + a.w * w3.y;
            acc[i].z += a.x * w0.z + a.y * w1.z + a.z * w2.z + a.w * w3.z;
            acc[i].w += a.x * w0.w + a.y * w1.w + a.z * w2.w + a.w * w3.w;
        }
    }

    #pragma unroll
    for (int i = 0; i < RPT; ++i) {
        int gr = row0 + rt * RPT + i;
        if (gr < NN) ((float4*)(out + (size_t)gr * DOUT))[cg] = acc[i];
    }
}

// ---------------- pull aggregation: out[i] = bias + sum_e val[e]*hin[col[e]] ----------------
// one wave per node; F=128 -> float2/lane, F=64 -> float/lane.

template <int F, bool RELU>
__global__ __launch_bounds__(256) void agg_kernel(const float* __restrict__ hin,
                                                  const int* __restrict__ row_ptr,
                                                  const int* __restrict__ col,
                                                  const float* __restrict__ val,
                                                  const float* __restrict__ bias,
                                                  float* __restrict__ out) {
    int wid = blockIdx.x * 4 + (threadIdx.x >> 6);
    if (wid >= NN) return;
    int lane = threadIdx.x & 63;
    int beg = row_ptr[wid];
    int end = row_ptr[wid + 1];

    if constexpr (F == 128) {
        float ax = 0.f, ay = 0.f;
        int e = beg;
        for (; e + 2 <= end; e += 2) {
            int c0 = col[e], c1 = col[e + 1];
            float w0 = val[e], w1 = val[e + 1];
            float2 v0 = ((const float2*)(hin + (size_t)c0 * 128))[lane];
            float2 v1 = ((const float2*)(hin + (size_t)c1 * 128))[lane];
            ax += w0 * v0.x; ay += w0 * v0.y;
            ax += w1 * v1.x; ay += w1 * v1.y;
        }
        if (e < end) {
            int c0 = col[e]; float w0 = val[e];
            float2 v0 = ((const float2*)(hin + (size_t)c0 * 128))[lane];
            ax += w0 * v0.x; ay += w0 * v0.y;
        }
        float2 b = ((const float2*)bias)[lane];
        ax += b.x; ay += b.y;
        if (RELU) { ax = fmaxf(ax, 0.f); ay = fmaxf(ay, 0.f); }
        float2 o; o.x = ax; o.y = ay;
        ((float2*)(out + (size_t)wid * 128))[lane] = o;
    } else {
        float a = 0.f;
        int e = beg;
        for (; e + 2 <= end; e += 2) {
            int c0 = col[e], c1 = col[e + 1];
            float w0 = val[e], w1 = val[e + 1];
            a += w0 * hin[(size_t)c0 * 64 + lane];
            a += w1 * hin[(size_t)c1 * 64 + lane];
        }
        if (e < end) a += val[e] * hin[(size_t)col[e] * 64 + lane];
        a += bias[lane];
        if (RELU) a = fmaxf(a, 0.f);
        out[(size_t)wid * 64 + lane] = a;
    }
}

// ---------------- launch ----------------

extern "C" void kernel_launch(void* const* d_in, const int* in_sizes, int n_in,
                              void* d_out, int out_size, void* d_ws, size_t ws_size,
                              hipStream_t stream) {
    const float* x  = (const float*)d_in[0];
    const int*   ei = (const int*)d_in[1];     // [2, NE], row0=src, row1=dst
    const float* W1 = (const float*)d_in[2];
    const float* b1 = (const float*)d_in[3];
    const float* W2 = (const float*)d_in[4];
    const float* b2 = (const float*)d_in[5];
    const float* W3 = (const float*)d_in[6];
    const float* b3 = (const float*)d_in[7];
    float* out = (float*)d_out;

    char* w = (char*)d_ws;
    int*   cnt     = (int*)  (w + 0x000000);                 // N ints
    int*   row_ptr = (int*)  (w + 0x040000);                 // N+1 ints
    int*   cursor  = (int*)  (w + 0x080000);                 // N ints
    float* dinv    = (float*)(w + 0x0C0000);                 // N floats
    int*   col     = (int*)  (w + 0x100000);                 // NTOT ints (3.4MB)
    float* valv    = (float*)(w + 0x480000);                 // NTOT floats (3.4MB)
    float* bufA    = (float*)(w + 0x800000);                 // N*128 fp32 (25.6MB)
    float* bufB    = (float*)(w + 0x800000 + 0x1A00000);     // N*128 fp32 (25.6MB)

    const int* src = ei;
    const int* dst = ei + NE;

    hipMemsetAsync(cnt, 0, NN * sizeof(int), stream);
    hist_kernel<<<(NE + 255) / 256, 256, 0, stream>>>(dst, cnt);
    scan_kernel<<<1, 1024, 0, stream>>>(cnt, row_ptr, dinv);
    self_kernel<<<(NN + 255) / 256, 256, 0, stream>>>(row_ptr, dinv, cursor, col, valv);
    scatter_kernel<<<(NE + 255) / 256, 256, 0, stream>>>(src, dst, dinv, cursor, col, valv);

    // layer 1: x @ W1 -> bufA ; aggregate+b1+relu -> bufB
    gemm_kernel<128, 8><<<(NN + 63) / 64, 256, 0, stream>>>(x, W1, bufA);
    agg_kernel<128, true><<<(NN + 3) / 4, 256, 0, stream>>>(bufA, row_ptr, col, valv, b1, bufB);
    // layer 2
    gemm_kernel<128, 8><<<(NN + 63) / 64, 256, 0, stream>>>(bufB, W2, bufA);
    agg_kernel<128, true><<<(NN + 3) / 4, 256, 0, stream>>>(bufA, row_ptr, col, valv, b2, bufB);
    // layer 3: 128 -> 64, no relu, straight to out
    gemm_kernel<64, 4><<<(NN + 63) / 64, 256, 0, stream>>>(bufB, W3, bufA);
    agg_kernel<64, false><<<(NN + 3) / 4, 256, 0, stream>>>(bufA, row_ptr, col, valv, b3, out);
}

// Round 2
// 453.059 us; speedup vs baseline: 1.1910x; 1.1910x over previous
//
#include <hip/hip_runtime.h>
#include <math.h>

#define NN 50000
#define NE 800000
#define NTOT (NN + NE)   // 850000 CSR entries (edges + self loops)
#define NB  ((NN + 255) / 256)   // 196 scan blocks

// ---------------- CSR build ----------------

__global__ __launch_bounds__(256) void hist_kernel(const int* __restrict__ dst,
                                                   int* __restrict__ cnt) {
    int e = blockIdx.x * 256 + threadIdx.x;
    if (e < NE) atomicAdd(&cnt[dst[e]], 1);
}

// Pass 1: per-block reduce of (cnt[i]+1) -> bsum[blockIdx]
__global__ __launch_bounds__(256) void scan1_kernel(const int* __restrict__ cnt,
                                                    int* __restrict__ bsum) {
    __shared__ int tmp[256];
    int t = threadIdx.x;
    int i = blockIdx.x * 256 + t;
    int v = (i < NN) ? (cnt[i] + 1) : 0;
    tmp[t] = v;
    __syncthreads();
    #pragma unroll
    for (int s = 128; s > 0; s >>= 1) {
        if (t < s) tmp[t] += tmp[t + s];
        __syncthreads();
    }
    if (t == 0) bsum[blockIdx.x] = tmp[0];
}

// Pass 2: one block scans bsum[0..NB-1] -> boff (exclusive)
__global__ __launch_bounds__(256) void scan2_kernel(const int* __restrict__ bsum,
                                                    int* __restrict__ boff) {
    __shared__ int tmp[256];
    int t = threadIdx.x;
    int v = (t < NB) ? bsum[t] : 0;
    tmp[t] = v;
    __syncthreads();
    #pragma unroll
    for (int s = 1; s < 256; s <<= 1) {
        int u = (t >= s) ? tmp[t - s] : 0;
        __syncthreads();
        tmp[t] += u;
        __syncthreads();
    }
    if (t < NB) boff[t] = tmp[t] - v;   // exclusive prefix
}

// Pass 3: per-block exclusive scan + block offset -> row_ptr; dinv = rsqrtf(deg)
__global__ __launch_bounds__(256) void scan3_kernel(const int* __restrict__ cnt,
                                                    const int* __restrict__ boff,
                                                    int* __restrict__ row_ptr,
                                                    float* __restrict__ dinv) {
    __shared__ int tmp[256];
    int t = threadIdx.x;
    int i = blockIdx.x * 256 + t;
    int v = (i < NN) ? (cnt[i] + 1) : 0;
    tmp[t] = v;
    __syncthreads();
    #pragma unroll
    for (int s = 1; s < 256; s <<= 1) {
        int u = (t >= s) ? tmp[t - s] : 0;
        __syncthreads();
        tmp[t] += u;
        __syncthreads();
    }
    if (i < NN) {
        row_ptr[i] = boff[blockIdx.x] + tmp[t] - v;   // exclusive
        dinv[i] = rsqrtf((float)v);
    }
    if (i == 0) row_ptr[NN] = NTOT;   // statically known total
}

// Place self loop at row start, init cursor.
__global__ __launch_bounds__(256) void self_kernel(const int* __restrict__ row_ptr,
                                                   const float* __restrict__ dinv,
                                                   int* __restrict__ cursor,
                                                   int* __restrict__ col,
                                                   float* __restrict__ val) {
    int i = blockIdx.x * 256 + threadIdx.x;
    if (i < NN) {
        int p = row_ptr[i];
        col[p] = i;
        float di = dinv[i];
        val[p] = di * di;
        cursor[i] = p + 1;
    }
}

__global__ __launch_bounds__(256) void scatter_kernel(const int* __restrict__ src,
                                                      const int* __restrict__ dst,
                                                      const float* __restrict__ dinv,
                                                      int* __restrict__ cursor,
                                                      int* __restrict__ col,
                                                      float* __restrict__ val) {
    int e = blockIdx.x * 256 + threadIdx.x;
    if (e < NE) {
        int s = src[e], d = dst[e];
        int p = atomicAdd(&cursor[d], 1);
        col[p] = s;
        val[p] = dinv[s] * dinv[d];
    }
}

// ---------------- dense GEMM: out[N x DOUT] = A[N x 128] @ W[128 x DOUT] ----------------

template <int DOUT, int RPT>
__global__ __launch_bounds__(256) void gemm_kernel(const float* __restrict__ A,
                                                   const float* __restrict__ W,
                                                   float* __restrict__ out) {
    constexpr int CG = DOUT / 4;      // 32 or 16
    constexpr int RT = 256 / CG;      // 8 or 16
    constexpr int ROWS = RT * RPT;    // 64 rows/block
    constexpr int LD = 132;
    __shared__ float lds[ROWS * LD];
    const int t = threadIdx.x;
    const int row0 = blockIdx.x * ROWS;

    #pragma unroll
    for (int j = 0; j < ROWS / 8; ++j) {
        int idx4 = j * 256 + t;
        int r = idx4 >> 5, c4 = idx4 & 31;
        int gr = row0 + r;
        float4 v = make_float4(0.f, 0.f, 0.f, 0.f);
        if (gr < NN) v = ((const float4*)(A + (size_t)gr * 128))[c4];
        ((float4*)(lds + r * LD))[c4] = v;
    }
    __syncthreads();

    const int cg = t % CG;
    const int rt = t / CG;
    const float4* Wv = (const float4*)W;
    float4 acc[RPT];
    #pragma unroll
    for (int i = 0; i < RPT; ++i) acc[i] = make_float4(0.f, 0.f, 0.f, 0.f);

    for (int k0 = 0; k0 < 128; k0 += 4) {
        float4 w0 = Wv[(k0 + 0) * CG + cg];
        float4 w1 = Wv[(k0 + 1) * CG + cg];
        float4 w2 = Wv[(k0 + 2) * CG + cg];
        float4 w3 = Wv[(k0 + 3) * CG + cg];
        #pragma unroll
        for (int i = 0; i < RPT; ++i) {
            const float* lr = lds + (rt * RPT + i) * LD;
            float4 a = ((const float4*)lr)[k0 >> 2];
            acc[i].x += a.x * w0.x + a.y * w1.x + a.z * w2.x + a.w * w3.x;
            acc[i].y += a.x * w0.y + a.y * w1.y + a.z * w2.y + a.w * w3.y;
            acc[i].z += a.x * w0.z + a.y * w1.z + a.z * w2.z + a.w * w3.z;
            acc[i].w += a.x * w0.w + a.y * w1.w + a.z * w2.w + a.w * w3.w;
        }
    }

    #pragma unroll
    for (int i = 0; i < RPT; ++i) {
        int gr = row0 + rt * RPT + i;
        if (gr < NN) ((float4*)(out + (size_t)gr * DOUT))[cg] = acc[i];
    }
}

// ---------------- pull aggregation: out[i] = bias + sum_e val[e]*hin[col[e]] ----------------

template <int F, bool RELU>
__global__ __launch_bounds__(256) void agg_kernel(const float* __restrict__ hin,
                                                  const int* __restrict__ row_ptr,
                                                  const int* __restrict__ col,
                                                  const float* __restrict__ val,
                                                  const float* __restrict__ bias,
                                                  float* __restrict__ out) {
    int wid = blockIdx.x * 4 + (threadIdx.x >> 6);
    if (wid >= NN) return;
    int lane = threadIdx.x & 63;
    int beg = row_ptr[wid];
    int end = row_ptr[wid + 1];

    if constexpr (F == 128) {
        float ax = 0.f, ay = 0.f;
        int e = beg;
        for (; e + 2 <= end; e += 2) {
            int c0 = col[e], c1 = col[e + 1];
            float w0 = val[e], w1 = val[e + 1];
            float2 v0 = ((const float2*)(hin + (size_t)c0 * 128))[lane];
            float2 v1 = ((const float2*)(hin + (size_t)c1 * 128))[lane];
            ax += w0 * v0.x; ay += w0 * v0.y;
            ax += w1 * v1.x; ay += w1 * v1.y;
        }
        if (e < end) {
            int c0 = col[e]; float w0 = val[e];
            float2 v0 = ((const float2*)(hin + (size_t)c0 * 128))[lane];
            ax += w0 * v0.x; ay += w0 * v0.y;
        }
        float2 b = ((const float2*)bias)[lane];
        ax += b.x; ay += b.y;
        if (RELU) { ax = fmaxf(ax, 0.f); ay = fmaxf(ay, 0.f); }
        float2 o; o.x = ax; o.y = ay;
        ((float2*)(out + (size_t)wid * 128))[lane] = o;
    } else {
        float a = 0.f;
        int e = beg;
        for (; e + 2 <= end; e += 2) {
            int c0 = col[e], c1 = col[e + 1];
            float w0 = val[e], w1 = val[e + 1];
            a += w0 * hin[(size_t)c0 * 64 + lane];
            a += w1 * hin[(size_t)c1 * 64 + lane];
        }
        if (e < end) a += val[e] * hin[(size_t)col[e] * 64 + lane];
        a += bias[lane];
        if (RELU) a = fmaxf(a, 0.f);
        out[(size_t)wid * 64 + lane] = a;
    }
}

// ---------------- launch ----------------

extern "C" void kernel_launch(void* const* d_in, const int* in_sizes, int n_in,
                              void* d_out, int out_size, void* d_ws, size_t ws_size,
                              hipStream_t stream) {
    const float* x  = (const float*)d_in[0];
    const int*   ei = (const int*)d_in[1];     // [2, NE], row0=src, row1=dst
    const float* W1 = (const float*)d_in[2];
    const float* b1 = (const float*)d_in[3];
    const float* W2 = (const float*)d_in[4];
    const float* b2 = (const float*)d_in[5];
    const float* W3 = (const float*)d_in[6];
    const float* b3 = (const float*)d_in[7];
    float* out = (float*)d_out;

    char* w = (char*)d_ws;
    int*   cnt     = (int*)  (w + 0x000000);                 // N ints
    int*   row_ptr = (int*)  (w + 0x040000);                 // N+1 ints
    int*   cursor  = (int*)  (w + 0x080000);                 // N ints
    float* dinv    = (float*)(w + 0x0C0000);                 // N floats
    int*   bsum    = (int*)  (w + 0x0F1000);                 // NB ints
    int*   boff    = (int*)  (w + 0x0F2000);                 // NB ints
    int*   col     = (int*)  (w + 0x100000);                 // NTOT ints (3.4MB)
    float* valv    = (float*)(w + 0x480000);                 // NTOT floats (3.4MB)
    float* bufA    = (float*)(w + 0x800000);                 // N*128 fp32 (25.6MB)
    float* bufB    = (float*)(w + 0x800000 + 0x1A00000);     // N*128 fp32 (25.6MB)

    const int* src = ei;
    const int* dst = ei + NE;

    hipMemsetAsync(cnt, 0, NN * sizeof(int), stream);
    hist_kernel<<<(NE + 255) / 256, 256, 0, stream>>>(dst, cnt);
    scan1_kernel<<<NB, 256, 0, stream>>>(cnt, bsum);
    scan2_kernel<<<1, 256, 0, stream>>>(bsum, boff);
    scan3_kernel<<<NB, 256, 0, stream>>>(cnt, boff, row_ptr, dinv);
    self_kernel<<<(NN + 255) / 256, 256, 0, stream>>>(row_ptr, dinv, cursor, col, valv);
    scatter_kernel<<<(NE + 255) / 256, 256, 0, stream>>>(src, dst, dinv, cursor, col, valv);

    // layer 1: x @ W1 -> bufA ; aggregate+b1+relu -> bufB
    gemm_kernel<128, 8><<<(NN + 63) / 64, 256, 0, stream>>>(x, W1, bufA);
    agg_kernel<128, true><<<(NN + 3) / 4, 256, 0, stream>>>(bufA, row_ptr, col, valv, b1, bufB);
    // layer 2
    gemm_kernel<128, 8><<<(NN + 63) / 64, 256, 0, stream>>>(bufB, W2, bufA);
    agg_kernel<128, true><<<(NN + 3) / 4, 256, 0, stream>>>(bufA, row_ptr, col, valv, b2, bufB);
    // layer 3: 128 -> 64, no relu, straight to out
    gemm_kernel<64, 4><<<(NN + 63) / 64, 256, 0, stream>>>(bufB, W3, bufA);
    agg_kernel<64, false><<<(NN + 3) / 4, 256, 0, stream>>>(bufA, row_ptr, col, valv, b3, out);
}

// Round 3
// 415.334 us; speedup vs baseline: 1.2992x; 1.0908x over previous
//
#include <hip/hip_runtime.h>
#include <math.h>

#define NN 50000
#define NE 800000
#define NTOT (NN + NE)   // 850000 CSR entries (edges + self loops)
#define NB  ((NN + 255) / 256)   // 196 scan blocks

// ---------------- CSR build ----------------

__global__ __launch_bounds__(256) void hist_kernel(const int* __restrict__ dst,
                                                   int* __restrict__ cnt) {
    int e = blockIdx.x * 256 + threadIdx.x;
    if (e < NE) atomicAdd(&cnt[dst[e]], 1);
}

// Pass 1: per-block reduce of (cnt[i]+1) -> bsum[blockIdx]
__global__ __launch_bounds__(256) void scan1_kernel(const int* __restrict__ cnt,
                                                    int* __restrict__ bsum) {
    __shared__ int tmp[256];
    int t = threadIdx.x;
    int i = blockIdx.x * 256 + t;
    int v = (i < NN) ? (cnt[i] + 1) : 0;
    tmp[t] = v;
    __syncthreads();
    #pragma unroll
    for (int s = 128; s > 0; s >>= 1) {
        if (t < s) tmp[t] += tmp[t + s];
        __syncthreads();
    }
    if (t == 0) bsum[blockIdx.x] = tmp[0];
}

// Pass 2: one block scans bsum[0..NB-1] -> boff (exclusive)
__global__ __launch_bounds__(256) void scan2_kernel(const int* __restrict__ bsum,
                                                    int* __restrict__ boff) {
    __shared__ int tmp[256];
    int t = threadIdx.x;
    int v = (t < NB) ? bsum[t] : 0;
    tmp[t] = v;
    __syncthreads();
    #pragma unroll
    for (int s = 1; s < 256; s <<= 1) {
        int u = (t >= s) ? tmp[t - s] : 0;
        __syncthreads();
        tmp[t] += u;
        __syncthreads();
    }
    if (t < NB) boff[t] = tmp[t] - v;   // exclusive prefix
}

// Pass 3: per-block exclusive scan + block offset -> row_ptr; dinv = rsqrtf(deg)
__global__ __launch_bounds__(256) void scan3_kernel(const int* __restrict__ cnt,
                                                    const int* __restrict__ boff,
                                                    int* __restrict__ row_ptr,
                                                    float* __restrict__ dinv) {
    __shared__ int tmp[256];
    int t = threadIdx.x;
    int i = blockIdx.x * 256 + t;
    int v = (i < NN) ? (cnt[i] + 1) : 0;
    tmp[t] = v;
    __syncthreads();
    #pragma unroll
    for (int s = 1; s < 256; s <<= 1) {
        int u = (t >= s) ? tmp[t - s] : 0;
        __syncthreads();
        tmp[t] += u;
        __syncthreads();
    }
    if (i < NN) {
        row_ptr[i] = boff[blockIdx.x] + tmp[t] - v;   // exclusive
        dinv[i] = rsqrtf((float)v);
    }
    if (i == 0) row_ptr[NN] = NTOT;   // statically known total
}

// Place self loop at row start, init cursor.
__global__ __launch_bounds__(256) void self_kernel(const int* __restrict__ row_ptr,
                                                   const float* __restrict__ dinv,
                                                   int* __restrict__ cursor,
                                                   int* __restrict__ col,
                                                   float* __restrict__ val) {
    int i = blockIdx.x * 256 + threadIdx.x;
    if (i < NN) {
        int p = row_ptr[i];
        col[p] = i;
        float di = dinv[i];
        val[p] = di * di;
        cursor[i] = p + 1;
    }
}

__global__ __launch_bounds__(256) void scatter_kernel(const int* __restrict__ src,
                                                      const int* __restrict__ dst,
                                                      const float* __restrict__ dinv,
                                                      int* __restrict__ cursor,
                                                      int* __restrict__ col,
                                                      float* __restrict__ val) {
    int e = blockIdx.x * 256 + threadIdx.x;
    if (e < NE) {
        int s = src[e], d = dst[e];
        int p = atomicAdd(&cursor[d], 1);
        col[p] = s;
        val[p] = dinv[s] * dinv[d];
    }
}

// ---------------- dense GEMM: out[N x DOUT] = A[N x 128] @ W[128 x DOUT] ----------------

template <int DOUT, int RPT>
__global__ __launch_bounds__(256) void gemm_kernel(const float* __restrict__ A,
                                                   const float* __restrict__ W,
                                                   float* __restrict__ out) {
    constexpr int CG = DOUT / 4;      // 32 or 16
    constexpr int RT = 256 / CG;      // 8 or 16
    constexpr int ROWS = RT * RPT;    // 64 rows/block
    constexpr int LD = 132;
    __shared__ float lds[ROWS * LD];
    const int t = threadIdx.x;
    const int row0 = blockIdx.x * ROWS;

    #pragma unroll
    for (int j = 0; j < ROWS / 8; ++j) {
        int idx4 = j * 256 + t;
        int r = idx4 >> 5, c4 = idx4 & 31;
        int gr = row0 + r;
        float4 v = make_float4(0.f, 0.f, 0.f, 0.f);
        if (gr < NN) v = ((const float4*)(A + (size_t)gr * 128))[c4];
        ((float4*)(lds + r * LD))[c4] = v;
    }
    __syncthreads();

    const int cg = t % CG;
    const int rt = t / CG;
    const float4* Wv = (const float4*)W;
    float4 acc[RPT];
    #pragma unroll
    for (int i = 0; i < RPT; ++i) acc[i] = make_float4(0.f, 0.f, 0.f, 0.f);

    for (int k0 = 0; k0 < 128; k0 += 4) {
        float4 w0 = Wv[(k0 + 0) * CG + cg];
        float4 w1 = Wv[(k0 + 1) * CG + cg];
        float4 w2 = Wv[(k0 + 2) * CG + cg];
        float4 w3 = Wv[(k0 + 3) * CG + cg];
        #pragma unroll
        for (int i = 0; i < RPT; ++i) {
            const float* lr = lds + (rt * RPT + i) * LD;
            float4 a = ((const float4*)lr)[k0 >> 2];
            acc[i].x += a.x * w0.x + a.y * w1.x + a.z * w2.x + a.w * w3.x;
            acc[i].y += a.x * w0.y + a.y * w1.y + a.z * w2.y + a.w * w3.y;
            acc[i].z += a.x * w0.z + a.y * w1.z + a.z * w2.z + a.w * w3.z;
            acc[i].w += a.x * w0.w + a.y * w1.w + a.z * w2.w + a.w * w3.w;
        }
    }

    #pragma unroll
    for (int i = 0; i < RPT; ++i) {
        int gr = row0 + rt * RPT + i;
        if (gr < NN) ((float4*)(out + (size_t)gr * DOUT))[cg] = acc[i];
    }
}

// ---------------- pull aggregation: out[i] = bias + sum_e val[e]*hin[col[e]] ----------------
// GPL lanes per node-group, float4 per lane (GPL*4 == F). 256/GPL groups per block.
// 4-edge unroll => 4 independent row-gathers in flight per group.

template <int F, bool RELU>
__global__ __launch_bounds__(256) void agg_kernel(const float* __restrict__ hin,
                                                  const int* __restrict__ row_ptr,
                                                  const int* __restrict__ col,
                                                  const float* __restrict__ val,
                                                  const float* __restrict__ bias,
                                                  float* __restrict__ out) {
    constexpr int GPL = F / 4;                 // lanes per group: 32 (F=128) or 16 (F=64)
    constexpr int GPB = 256 / GPL;             // groups per block: 8 or 16
    const int t = threadIdx.x;
    const int group = t / GPL;
    const int lane  = t % GPL;
    const int wid = blockIdx.x * GPB + group;

    int beg = 0, end = 0;
    if (wid < NN) { beg = row_ptr[wid]; end = row_ptr[wid + 1]; }

    float4 acc = make_float4(0.f, 0.f, 0.f, 0.f);
    const float4* hv = (const float4*)hin;
    int e = beg;
    for (; e + 4 <= end; e += 4) {
        int c0 = col[e],     c1 = col[e + 1];
        int c2 = col[e + 2], c3 = col[e + 3];
        float w0 = val[e],     w1 = val[e + 1];
        float w2 = val[e + 2], w3 = val[e + 3];
        float4 v0 = hv[(size_t)c0 * GPL + lane];
        float4 v1 = hv[(size_t)c1 * GPL + lane];
        float4 v2 = hv[(size_t)c2 * GPL + lane];
        float4 v3 = hv[(size_t)c3 * GPL + lane];
        acc.x += w0 * v0.x + w1 * v1.x + w2 * v2.x + w3 * v3.x;
        acc.y += w0 * v0.y + w1 * v1.y + w2 * v2.y + w3 * v3.y;
        acc.z += w0 * v0.z + w1 * v1.z + w2 * v2.z + w3 * v3.z;
        acc.w += w0 * v0.w + w1 * v1.w + w2 * v2.w + w3 * v3.w;
    }
    for (; e < end; ++e) {
        int c0 = col[e]; float w0 = val[e];
        float4 v0 = hv[(size_t)c0 * GPL + lane];
        acc.x += w0 * v0.x; acc.y += w0 * v0.y;
        acc.z += w0 * v0.z; acc.w += w0 * v0.w;
    }

    if (wid < NN) {
        float4 b = ((const float4*)bias)[lane];
        acc.x += b.x; acc.y += b.y; acc.z += b.z; acc.w += b.w;
        if (RELU) {
            acc.x = fmaxf(acc.x, 0.f); acc.y = fmaxf(acc.y, 0.f);
            acc.z = fmaxf(acc.z, 0.f); acc.w = fmaxf(acc.w, 0.f);
        }
        ((float4*)(out + (size_t)wid * F))[lane] = acc;
    }
}

// ---------------- launch ----------------

extern "C" void kernel_launch(void* const* d_in, const int* in_sizes, int n_in,
                              void* d_out, int out_size, void* d_ws, size_t ws_size,
                              hipStream_t stream) {
    const float* x  = (const float*)d_in[0];
    const int*   ei = (const int*)d_in[1];     // [2, NE], row0=src, row1=dst
    const float* W1 = (const float*)d_in[2];
    const float* b1 = (const float*)d_in[3];
    const float* W2 = (const float*)d_in[4];
    const float* b2 = (const float*)d_in[5];
    const float* W3 = (const float*)d_in[6];
    const float* b3 = (const float*)d_in[7];
    float* out = (float*)d_out;

    char* w = (char*)d_ws;
    int*   cnt     = (int*)  (w + 0x000000);                 // N ints
    int*   row_ptr = (int*)  (w + 0x040000);                 // N+1 ints
    int*   cursor  = (int*)  (w + 0x080000);                 // N ints
    float* dinv    = (float*)(w + 0x0C0000);                 // N floats
    int*   bsum    = (int*)  (w + 0x0F1000);                 // NB ints
    int*   boff    = (int*)  (w + 0x0F2000);                 // NB ints
    int*   col     = (int*)  (w + 0x100000);                 // NTOT ints (3.4MB)
    float* valv    = (float*)(w + 0x480000);                 // NTOT floats (3.4MB)
    float* bufA    = (float*)(w + 0x800000);                 // N*128 fp32 (25.6MB)
    float* bufB    = (float*)(w + 0x800000 + 0x1A00000);     // N*128 fp32 (25.6MB)

    const int* src = ei;
    const int* dst = ei + NE;

    hipMemsetAsync(cnt, 0, NN * sizeof(int), stream);
    hist_kernel<<<(NE + 255) / 256, 256, 0, stream>>>(dst, cnt);
    scan1_kernel<<<NB, 256, 0, stream>>>(cnt, bsum);
    scan2_kernel<<<1, 256, 0, stream>>>(bsum, boff);
    scan3_kernel<<<NB, 256, 0, stream>>>(cnt, boff, row_ptr, dinv);
    self_kernel<<<(NN + 255) / 256, 256, 0, stream>>>(row_ptr, dinv, cursor, col, valv);
    scatter_kernel<<<(NE + 255) / 256, 256, 0, stream>>>(src, dst, dinv, cursor, col, valv);

    // layer 1: x @ W1 -> bufA ; aggregate+b1+relu -> bufB
    gemm_kernel<128, 8><<<(NN + 63) / 64, 256, 0, stream>>>(x, W1, bufA);
    agg_kernel<128, true><<<(NN + 7) / 8, 256, 0, stream>>>(bufA, row_ptr, col, valv, b1, bufB);
    // layer 2
    gemm_kernel<128, 8><<<(NN + 63) / 64, 256, 0, stream>>>(bufB, W2, bufA);
    agg_kernel<128, true><<<(NN + 7) / 8, 256, 0, stream>>>(bufA, row_ptr, col, valv, b2, bufB);
    // layer 3: 128 -> 64, no relu, straight to out
    gemm_kernel<64, 4><<<(NN + 63) / 64, 256, 0, stream>>>(bufB, W3, bufA);
    agg_kernel<64, false><<<(NN + 15) / 16, 256, 0, stream>>>(bufA, row_ptr, col, valv, b3, out);
}

// Round 4
// 396.666 us; speedup vs baseline: 1.3604x; 1.0471x over previous
//
#include <hip/hip_runtime.h>
#include <math.h>

#define NN 50000
#define NE 800000
#define NB  ((NN + 255) / 256)   // 196 scan blocks

// CSR rows padded to multiple of 8 with (col=0, w=0) entries; row 0 stays
// L1-hot so pad gathers are ~free. Edges stored packed as int2{col, f32bits(w)}.

// ---------------- CSR build ----------------

__global__ __launch_bounds__(256) void hist_kernel(const int* __restrict__ dst,
                                                   int* __restrict__ cnt) {
    int e = blockIdx.x * 256 + threadIdx.x;
    if (e < NE) atomicAdd(&cnt[dst[e]], 1);
}

// Pass 1: per-block reduce of padded degree -> bsum[blockIdx]
__global__ __launch_bounds__(256) void scan1_kernel(const int* __restrict__ cnt,
                                                    int* __restrict__ bsum) {
    __shared__ int tmp[256];
    int t = threadIdx.x;
    int i = blockIdx.x * 256 + t;
    int v = (i < NN) ? ((cnt[i] + 1 + 7) & ~7) : 0;
    tmp[t] = v;
    __syncthreads();
    #pragma unroll
    for (int s = 128; s > 0; s >>= 1) {
        if (t < s) tmp[t] += tmp[t + s];
        __syncthreads();
    }
    if (t == 0) bsum[blockIdx.x] = tmp[0];
}

// Pass 2: one block scans bsum[0..NB-1] -> boff (exclusive)
__global__ __launch_bounds__(256) void scan2_kernel(const int* __restrict__ bsum,
                                                    int* __restrict__ boff) {
    __shared__ int tmp[256];
    int t = threadIdx.x;
    int v = (t < NB) ? bsum[t] : 0;
    tmp[t] = v;
    __syncthreads();
    #pragma unroll
    for (int s = 1; s < 256; s <<= 1) {
        int u = (t >= s) ? tmp[t - s] : 0;
        __syncthreads();
        tmp[t] += u;
        __syncthreads();
    }
    if (t < NB) boff[t] = tmp[t] - v;   // exclusive prefix
}

// Pass 3: row_ptr (padded), dinv, self-loop edge, pad edges, cursor.
__global__ __launch_bounds__(256) void scan3_kernel(const int* __restrict__ cnt,
                                                    const int* __restrict__ boff,
                                                    int* __restrict__ row_ptr,
                                                    float* __restrict__ dinv,
                                                    int2* __restrict__ eg,
                                                    int* __restrict__ cursor) {
    __shared__ int tmp[256];
    int t = threadIdx.x;
    int i = blockIdx.x * 256 + t;
    int deg = (i < NN) ? (cnt[i] + 1) : 0;
    int vpad = (deg + 7) & ~7;
    tmp[t] = vpad;
    __syncthreads();
    #pragma unroll
    for (int s = 1; s < 256; s <<= 1) {
        int u = (t >= s) ? tmp[t - s] : 0;
        __syncthreads();
        tmp[t] += u;
        __syncthreads();
    }
    if (i < NN) {
        int rp = boff[blockIdx.x] + tmp[t] - vpad;   // exclusive
        row_ptr[i] = rp;
        float di = rsqrtf((float)deg);
        dinv[i] = di;
        int2 self; self.x = i; self.y = __float_as_int(di * di);
        eg[rp] = self;                                // self loop at row start
        cursor[i] = rp + 1;
        int2 pad; pad.x = 0; pad.y = 0;
        for (int p = rp + deg; p < rp + vpad; ++p) eg[p] = pad;
        if (i == NN - 1) row_ptr[NN] = rp + vpad;
    }
}

__global__ __launch_bounds__(256) void scatter_kernel(const int* __restrict__ src,
                                                      const int* __restrict__ dst,
                                                      const float* __restrict__ dinv,
                                                      int* __restrict__ cursor,
                                                      int2* __restrict__ eg) {
    int e = blockIdx.x * 256 + threadIdx.x;
    if (e < NE) {
        int s = src[e], d = dst[e];
        int p = atomicAdd(&cursor[d], 1);
        int2 pk; pk.x = s; pk.y = __float_as_int(dinv[s] * dinv[d]);
        eg[p] = pk;                                   // single 8B scattered store
    }
}

// ---------------- dense GEMM: out[N x DOUT] = A[N x 128] @ W[128 x DOUT] ----------------

template <int DOUT, int RPT>
__global__ __launch_bounds__(256) void gemm_kernel(const float* __restrict__ A,
                                                   const float* __restrict__ W,
                                                   float* __restrict__ out) {
    constexpr int CG = DOUT / 4;      // 32 or 16
    constexpr int RT = 256 / CG;      // 8 or 16
    constexpr int ROWS = RT * RPT;    // 64 rows/block
    constexpr int LD = 132;
    __shared__ float lds[ROWS * LD];
    const int t = threadIdx.x;
    const int row0 = blockIdx.x * ROWS;

    #pragma unroll
    for (int j = 0; j < ROWS / 8; ++j) {
        int idx4 = j * 256 + t;
        int r = idx4 >> 5, c4 = idx4 & 31;
        int gr = row0 + r;
        float4 v = make_float4(0.f, 0.f, 0.f, 0.f);
        if (gr < NN) v = ((const float4*)(A + (size_t)gr * 128))[c4];
        ((float4*)(lds + r * LD))[c4] = v;
    }
    __syncthreads();

    const int cg = t % CG;
    const int rt = t / CG;
    const float4* Wv = (const float4*)W;
    float4 acc[RPT];
    #pragma unroll
    for (int i = 0; i < RPT; ++i) acc[i] = make_float4(0.f, 0.f, 0.f, 0.f);

    for (int k0 = 0; k0 < 128; k0 += 4) {
        float4 w0 = Wv[(k0 + 0) * CG + cg];
        float4 w1 = Wv[(k0 + 1) * CG + cg];
        float4 w2 = Wv[(k0 + 2) * CG + cg];
        float4 w3 = Wv[(k0 + 3) * CG + cg];
        #pragma unroll
        for (int i = 0; i < RPT; ++i) {
            const float* lr = lds + (rt * RPT + i) * LD;
            float4 a = ((const float4*)lr)[k0 >> 2];
            acc[i].x += a.x * w0.x + a.y * w1.x + a.z * w2.x + a.w * w3.x;
            acc[i].y += a.x * w0.y + a.y * w1.y + a.z * w2.y + a.w * w3.y;
            acc[i].z += a.x * w0.z + a.y * w1.z + a.z * w2.z + a.w * w3.z;
            acc[i].w += a.x * w0.w + a.y * w1.w + a.z * w2.w + a.w * w3.w;
        }
    }

    #pragma unroll
    for (int i = 0; i < RPT; ++i) {
        int gr = row0 + rt * RPT + i;
        if (gr < NN) ((float4*)(out + (size_t)gr * DOUT))[cg] = acc[i];
    }
}

// ---------------- pull aggregation ----------------
// GPL lanes per node-group (float4/lane), rows padded to 8 edges:
// uniform 8-edge unrolled loop, 8 independent row-gathers in flight per group.

template <int F, bool RELU>
__global__ __launch_bounds__(256) void agg_kernel(const float* __restrict__ hin,
                                                  const int* __restrict__ row_ptr,
                                                  const int2* __restrict__ eg,
                                                  const float* __restrict__ bias,
                                                  float* __restrict__ out) {
    constexpr int GPL = F / 4;                 // 32 (F=128) or 16 (F=64)
    constexpr int GPB = 256 / GPL;             // 8 or 16
    const int t = threadIdx.x;
    const int group = t / GPL;
    const int lane  = t % GPL;
    const int wid = blockIdx.x * GPB + group;
    if (wid >= NN) return;

    const int beg = row_ptr[wid];
    const int end = row_ptr[wid + 1];          // (end-beg) % 8 == 0, beg % 8 == 0

    const float4* hv = (const float4*)hin;
    const int4* e4 = (const int4*)eg;          // 2 edges per int4, 16B-aligned
    float4 acc = make_float4(0.f, 0.f, 0.f, 0.f);

    for (int e = beg; e < end; e += 8) {
        int q = e >> 1;
        int4 p0 = e4[q + 0];
        int4 p1 = e4[q + 1];
        int4 p2 = e4[q + 2];
        int4 p3 = e4[q + 3];
        float4 v0 = hv[(size_t)p0.x * GPL + lane];
        float4 v1 = hv[(size_t)p0.z * GPL + lane];
        float4 v2 = hv[(size_t)p1.x * GPL + lane];
        float4 v3 = hv[(size_t)p1.z * GPL + lane];
        float4 v4 = hv[(size_t)p2.x * GPL + lane];
        float4 v5 = hv[(size_t)p2.z * GPL + lane];
        float4 v6 = hv[(size_t)p3.x * GPL + lane];
        float4 v7 = hv[(size_t)p3.z * GPL + lane];
        float w0 = __int_as_float(p0.y), w1 = __int_as_float(p0.w);
        float w2 = __int_as_float(p1.y), w3 = __int_as_float(p1.w);
        float w4 = __int_as_float(p2.y), w5 = __int_as_float(p2.w);
        float w6 = __int_as_float(p3.y), w7 = __int_as_float(p3.w);
        acc.x += w0*v0.x + w1*v1.x + w2*v2.x + w3*v3.x + w4*v4.x + w5*v5.x + w6*v6.x + w7*v7.x;
        acc.y += w0*v0.y + w1*v1.y + w2*v2.y + w3*v3.y + w4*v4.y + w5*v5.y + w6*v6.y + w7*v7.y;
        acc.z += w0*v0.z + w1*v1.z + w2*v2.z + w3*v3.z + w4*v4.z + w5*v5.z + w6*v6.z + w7*v7.z;
        acc.w += w0*v0.w + w1*v1.w + w2*v2.w + w3*v3.w + w4*v4.w + w5*v5.w + w6*v6.w + w7*v7.w;
    }

    float4 b = ((const float4*)bias)[lane];
    acc.x += b.x; acc.y += b.y; acc.z += b.z; acc.w += b.w;
    if (RELU) {
        acc.x = fmaxf(acc.x, 0.f); acc.y = fmaxf(acc.y, 0.f);
        acc.z = fmaxf(acc.z, 0.f); acc.w = fmaxf(acc.w, 0.f);
    }
    ((float4*)(out + (size_t)wid * F))[lane] = acc;
}

// ---------------- launch ----------------

extern "C" void kernel_launch(void* const* d_in, const int* in_sizes, int n_in,
                              void* d_out, int out_size, void* d_ws, size_t ws_size,
                              hipStream_t stream) {
    const float* x  = (const float*)d_in[0];
    const int*   ei = (const int*)d_in[1];     // [2, NE], row0=src, row1=dst
    const float* W1 = (const float*)d_in[2];
    const float* b1 = (const float*)d_in[3];
    const float* W2 = (const float*)d_in[4];
    const float* b2 = (const float*)d_in[5];
    const float* W3 = (const float*)d_in[6];
    const float* b3 = (const float*)d_in[7];
    float* out = (float*)d_out;

    char* w = (char*)d_ws;
    int*   cnt     = (int*)  (w + 0x000000);   // N ints
    int*   row_ptr = (int*)  (w + 0x040000);   // N+1 ints
    int*   cursor  = (int*)  (w + 0x080000);   // N ints
    float* dinv    = (float*)(w + 0x0C0000);   // N floats
    int*   bsum    = (int*)  (w + 0x0F1000);   // NB ints
    int*   boff    = (int*)  (w + 0x0F2000);   // NB ints
    int2*  eg      = (int2*) (w + 0x100000);   // <=1,150,000 int2 (9.2MB)
    float* bufA    = (float*)(w + 0xA00000);   // N*128 fp32 (25.6MB)
    float* bufB    = (float*)(w + 0x2280000);  // N*128 fp32 (25.6MB) ends ~61.7MB

    const int* src = ei;
    const int* dst = ei + NE;

    hipMemsetAsync(cnt, 0, NN * sizeof(int), stream);
    hist_kernel<<<(NE + 255) / 256, 256, 0, stream>>>(dst, cnt);
    scan1_kernel<<<NB, 256, 0, stream>>>(cnt, bsum);
    scan2_kernel<<<1, 256, 0, stream>>>(bsum, boff);
    scan3_kernel<<<NB, 256, 0, stream>>>(cnt, boff, row_ptr, dinv, eg, cursor);
    scatter_kernel<<<(NE + 255) / 256, 256, 0, stream>>>(src, dst, dinv, cursor, eg);

    // layer 1: x @ W1 -> bufA ; aggregate+b1+relu -> bufB
    gemm_kernel<128, 8><<<(NN + 63) / 64, 256, 0, stream>>>(x, W1, bufA);
    agg_kernel<128, true><<<(NN + 7) / 8, 256, 0, stream>>>(bufA, row_ptr, eg, b1, bufB);
    // layer 2
    gemm_kernel<128, 8><<<(NN + 63) / 64, 256, 0, stream>>>(bufB, W2, bufA);
    agg_kernel<128, true><<<(NN + 7) / 8, 256, 0, stream>>>(bufA, row_ptr, eg, b2, bufB);
    // layer 3: 128 -> 64, no relu, straight to out
    gemm_kernel<64, 4><<<(NN + 63) / 64, 256, 0, stream>>>(bufB, W3, bufA);
    agg_kernel<64, false><<<(NN + 15) / 16, 256, 0, stream>>>(bufA, row_ptr, eg, b3, out);
}

// Round 5
// 318.873 us; speedup vs baseline: 1.6922x; 1.2440x over previous
//
#include <hip/hip_runtime.h>
#include <math.h>

#define NN 50000
#define NE 800000
#define NB  ((NN + 255) / 256)   // 196 scan blocks

using bf8v = __attribute__((ext_vector_type(8))) short;   // 8 bf16 (4 VGPRs)
using f4v  = __attribute__((ext_vector_type(4))) float;   // 4 fp32 acc

__device__ inline unsigned short f2bf(float f) {          // RNE f32->bf16
    unsigned int u = __float_as_uint(f);
    u += 0x7FFFu + ((u >> 16) & 1u);
    return (unsigned short)(u >> 16);
}
__device__ inline float bflo(unsigned int d) { return __uint_as_float(d << 16); }
__device__ inline float bfhi(unsigned int d) { return __uint_as_float(d & 0xFFFF0000u); }

// ---------------- CSR build (rows padded to 8; edges packed int2{col, w}) ----------------

__global__ __launch_bounds__(256) void hist_kernel(const int* __restrict__ dst,
                                                   int* __restrict__ cnt) {
    int e = blockIdx.x * 256 + threadIdx.x;
    if (e < NE) atomicAdd(&cnt[dst[e]], 1);
}

__global__ __launch_bounds__(256) void scan1_kernel(const int* __restrict__ cnt,
                                                    int* __restrict__ bsum) {
    __shared__ int tmp[256];
    int t = threadIdx.x;
    int i = blockIdx.x * 256 + t;
    int v = (i < NN) ? ((cnt[i] + 1 + 7) & ~7) : 0;
    tmp[t] = v;
    __syncthreads();
    #pragma unroll
    for (int s = 128; s > 0; s >>= 1) {
        if (t < s) tmp[t] += tmp[t + s];
        __syncthreads();
    }
    if (t == 0) bsum[blockIdx.x] = tmp[0];
}

__global__ __launch_bounds__(256) void scan2_kernel(const int* __restrict__ bsum,
                                                    int* __restrict__ boff) {
    __shared__ int tmp[256];
    int t = threadIdx.x;
    int v = (t < NB) ? bsum[t] : 0;
    tmp[t] = v;
    __syncthreads();
    #pragma unroll
    for (int s = 1; s < 256; s <<= 1) {
        int u = (t >= s) ? tmp[t - s] : 0;
        __syncthreads();
        tmp[t] += u;
        __syncthreads();
    }
    if (t < NB) boff[t] = tmp[t] - v;
}

__global__ __launch_bounds__(256) void scan3_kernel(const int* __restrict__ cnt,
                                                    const int* __restrict__ boff,
                                                    int* __restrict__ row_ptr,
                                                    float* __restrict__ dinv,
                                                    int2* __restrict__ eg,
                                                    int* __restrict__ cursor) {
    __shared__ int tmp[256];
    int t = threadIdx.x;
    int i = blockIdx.x * 256 + t;
    int deg = (i < NN) ? (cnt[i] + 1) : 0;
    int vpad = (deg + 7) & ~7;
    tmp[t] = vpad;
    __syncthreads();
    #pragma unroll
    for (int s = 1; s < 256; s <<= 1) {
        int u = (t >= s) ? tmp[t - s] : 0;
        __syncthreads();
        tmp[t] += u;
        __syncthreads();
    }
    if (i < NN) {
        int rp = boff[blockIdx.x] + tmp[t] - vpad;
        row_ptr[i] = rp;
        float di = rsqrtf((float)deg);
        dinv[i] = di;
        int2 self; self.x = i; self.y = __float_as_int(di * di);
        eg[rp] = self;
        cursor[i] = rp + 1;
        int2 pad; pad.x = 0; pad.y = 0;
        for (int p = rp + deg; p < rp + vpad; ++p) eg[p] = pad;
        if (i == NN - 1) row_ptr[NN] = rp + vpad;
    }
}

__global__ __launch_bounds__(256) void scatter_kernel(const int* __restrict__ src,
                                                      const int* __restrict__ dst,
                                                      const float* __restrict__ dinv,
                                                      int* __restrict__ cursor,
                                                      int2* __restrict__ eg) {
    int e = blockIdx.x * 256 + threadIdx.x;
    if (e < NE) {
        int s = src[e], d = dst[e];
        int p = atomicAdd(&cursor[d], 1);
        int2 pk; pk.x = s; pk.y = __float_as_int(dinv[s] * dinv[d]);
        eg[p] = pk;
    }
}

// ---------------- MFMA bf16 GEMM (layers 1-2): out_bf16[N x 128] = A[N x 128] @ W[128 x 128] ----
// block = 256 thr (4 waves), 64 rows x 128 cols. W transposed to bf16 LDS (pad 136).
// Layouts (m89/m120-verified): A-frag A[m=lane&15][k=quad*8+j]; B-frag B[k=quad*8+j][n=lane&15];
// D: col=lane&15, row=quad*4+reg.

template <bool A_FP32>
__global__ __launch_bounds__(256) void mfma_gemm_kernel(const void* __restrict__ Ain,
                                                        const float* __restrict__ W,
                                                        unsigned short* __restrict__ out) {
    __shared__ unsigned short Wt[128 * 136];   // [n][k] bf16, padded
    __shared__ unsigned short Dt[64 * 136];    // [m][n] bf16, padded
    const int t = threadIdx.x;
    const int row0 = blockIdx.x * 64;

    // stage Wt = W^T (bf16). threads 0-127: k%8 in 0..3; 128-255: k%8 in 4..7
    {
        int n = t & 127;
        int kbase = (t >> 7) * 4;
        for (int kk = kbase; kk < 128; kk += 8) {
            float w0 = W[(kk + 0) * 128 + n];
            float w1 = W[(kk + 1) * 128 + n];
            float w2 = W[(kk + 2) * 128 + n];
            float w3 = W[(kk + 3) * 128 + n];
            unsigned int p0 = (unsigned int)f2bf(w0) | ((unsigned int)f2bf(w1) << 16);
            unsigned int p1 = (unsigned int)f2bf(w2) | ((unsigned int)f2bf(w3) << 16);
            *(unsigned int*)&Wt[n * 136 + kk]     = p0;
            *(unsigned int*)&Wt[n * 136 + kk + 2] = p1;
        }
    }
    __syncthreads();

    const int wave = t >> 6;
    const int lane = t & 63;
    const int m16  = lane & 15;
    const int quad = lane >> 4;
    const int arow = row0 + wave * 16 + m16;
    const int arowc = (arow < NN) ? arow : 0;

    f4v acc[8];
    #pragma unroll
    for (int i = 0; i < 8; ++i) acc[i] = (f4v)(0.0f);

    #pragma unroll
    for (int k0 = 0; k0 < 128; k0 += 32) {
        bf8v afrag;
        if (A_FP32) {
            const float* A = (const float*)Ain;
            const float4* ap = (const float4*)(A + (size_t)arowc * 128 + k0 + quad * 8);
            float4 a0 = ap[0], a1 = ap[1];
            afrag[0] = (short)f2bf(a0.x); afrag[1] = (short)f2bf(a0.y);
            afrag[2] = (short)f2bf(a0.z); afrag[3] = (short)f2bf(a0.w);
            afrag[4] = (short)f2bf(a1.x); afrag[5] = (short)f2bf(a1.y);
            afrag[6] = (short)f2bf(a1.z); afrag[7] = (short)f2bf(a1.w);
        } else {
            const unsigned short* A = (const unsigned short*)Ain;
            afrag = *(const bf8v*)(A + (size_t)arowc * 128 + k0 + quad * 8);
        }
        #pragma unroll
        for (int nt = 0; nt < 8; ++nt) {
            bf8v bfrag = *(const bf8v*)&Wt[(nt * 16 + m16) * 136 + k0 + quad * 8];
            acc[nt] = __builtin_amdgcn_mfma_f32_16x16x32_bf16(afrag, bfrag, acc[nt], 0, 0, 0);
        }
    }

    // D -> LDS (bf16)
    #pragma unroll
    for (int nt = 0; nt < 8; ++nt) {
        #pragma unroll
        for (int r = 0; r < 4; ++r) {
            Dt[(wave * 16 + quad * 4 + r) * 136 + nt * 16 + m16] = f2bf(acc[nt][r]);
        }
    }
    __syncthreads();

    // coalesced write-out: 64 rows x 256B; thread t does 64B of row t>>2
    {
        int r = t >> 2;
        int c = t & 3;
        int gr = row0 + r;
        if (gr < NN) {
            const uint4* s = (const uint4*)&Dt[r * 136] + c * 4;
            uint4* d = (uint4*)(out + (size_t)gr * 128) + c * 4;
            d[0] = s[0]; d[1] = s[1]; d[2] = s[2]; d[3] = s[3];
        }
    }
}

// ---------------- bf16 pull aggregation (layers 1-2) ----------------
// 16 lanes/node-group (8 bf16 feats per lane = 16B), 16 groups/block, 8-edge unroll.
// Reads bf16 h, accumulates fp32, writes bf16 z (+bias,+relu).

template <bool RELU>
__global__ __launch_bounds__(256) void agg_bf16_kernel(const unsigned short* __restrict__ hin,
                                                       const int* __restrict__ row_ptr,
                                                       const int2* __restrict__ eg,
                                                       const float* __restrict__ bias,
                                                       unsigned short* __restrict__ outb) {
    const int t = threadIdx.x;
    const int group = t >> 4;
    const int lane  = t & 15;
    const int wid = blockIdx.x * 16 + group;
    if (wid >= NN) return;

    const int beg = row_ptr[wid];
    const int end = row_ptr[wid + 1];
    const uint4* hv = (const uint4*)hin;      // 16 uint4 per row
    const int4* e4 = (const int4*)eg;

    float acc[8] = {0.f, 0.f, 0.f, 0.f, 0.f, 0.f, 0.f, 0.f};

    for (int e = beg; e < end; e += 8) {
        int q = e >> 1;
        int4 p0 = e4[q + 0];
        int4 p1 = e4[q + 1];
        int4 p2 = e4[q + 2];
        int4 p3 = e4[q + 3];
        uint4 g0 = hv[(size_t)p0.x * 16 + lane];
        uint4 g1 = hv[(size_t)p0.z * 16 + lane];
        uint4 g2 = hv[(size_t)p1.x * 16 + lane];
        uint4 g3 = hv[(size_t)p1.z * 16 + lane];
        uint4 g4 = hv[(size_t)p2.x * 16 + lane];
        uint4 g5 = hv[(size_t)p2.z * 16 + lane];
        uint4 g6 = hv[(size_t)p3.x * 16 + lane];
        uint4 g7 = hv[(size_t)p3.z * 16 + lane];
        float w0 = __int_as_float(p0.y), w1 = __int_as_float(p0.w);
        float w2 = __int_as_float(p1.y), w3 = __int_as_float(p1.w);
        float w4 = __int_as_float(p2.y), w5 = __int_as_float(p2.w);
        float w6 = __int_as_float(p3.y), w7 = __int_as_float(p3.w);
        #define ACCUM(G, W_) \
            acc[0] += W_ * bflo(G.x); acc[1] += W_ * bfhi(G.x); \
            acc[2] += W_ * bflo(G.y); acc[3] += W_ * bfhi(G.y); \
            acc[4] += W_ * bflo(G.z); acc[5] += W_ * bfhi(G.z); \
            acc[6] += W_ * bflo(G.w); acc[7] += W_ * bfhi(G.w);
        ACCUM(g0, w0) ACCUM(g1, w1) ACCUM(g2, w2) ACCUM(g3, w3)
        ACCUM(g4, w4) ACCUM(g5, w5) ACCUM(g6, w6) ACCUM(g7, w7)
        #undef ACCUM
    }

    const float4* bp = (const float4*)bias;
    float4 b0 = bp[lane * 2], b1 = bp[lane * 2 + 1];
    acc[0] += b0.x; acc[1] += b0.y; acc[2] += b0.z; acc[3] += b0.w;
    acc[4] += b1.x; acc[5] += b1.y; acc[6] += b1.z; acc[7] += b1.w;
    if (RELU) {
        #pragma unroll
        for (int j = 0; j < 8; ++j) acc[j] = fmaxf(acc[j], 0.f);
    }
    uint4 o;
    o.x = (unsigned int)f2bf(acc[0]) | ((unsigned int)f2bf(acc[1]) << 16);
    o.y = (unsigned int)f2bf(acc[2]) | ((unsigned int)f2bf(acc[3]) << 16);
    o.z = (unsigned int)f2bf(acc[4]) | ((unsigned int)f2bf(acc[5]) << 16);
    o.w = (unsigned int)f2bf(acc[6]) | ((unsigned int)f2bf(acc[7]) << 16);
    ((uint4*)(outb + (size_t)wid * 128))[lane] = o;
}

// ---------------- layer-3 GEMM (fp32 compute, bf16 A): h3[N x 64] = z2 @ W3 ----------------

__global__ __launch_bounds__(256) void gemm3_kernel(const unsigned short* __restrict__ Ab,
                                                    const float* __restrict__ W,
                                                    float* __restrict__ out) {
    constexpr int CG = 16;      // 64/4 col-groups
    constexpr int RT = 16;
    constexpr int RPT = 4;
    constexpr int ROWS = 64;
    constexpr int LD = 132;
    __shared__ float lds[ROWS * LD];
    const int t = threadIdx.x;
    const int row0 = blockIdx.x * ROWS;

    #pragma unroll
    for (int j = 0; j < ROWS / 8; ++j) {
        int idx4 = j * 256 + t;
        int r = idx4 >> 5, c4 = idx4 & 31;
        int gr = row0 + r;
        uint2 u = make_uint2(0u, 0u);
        if (gr < NN) u = ((const uint2*)(Ab + (size_t)gr * 128))[c4];
        float4 v;
        v.x = bflo(u.x); v.y = bfhi(u.x); v.z = bflo(u.y); v.w = bfhi(u.y);
        ((float4*)(lds + r * LD))[c4] = v;
    }
    __syncthreads();

    const int cg = t % CG;
    const int rt = t / CG;
    const float4* Wv = (const float4*)W;
    float4 acc[RPT];
    #pragma unroll
    for (int i = 0; i < RPT; ++i) acc[i] = make_float4(0.f, 0.f, 0.f, 0.f);

    for (int k0 = 0; k0 < 128; k0 += 4) {
        float4 w0 = Wv[(k0 + 0) * CG + cg];
        float4 w1 = Wv[(k0 + 1) * CG + cg];
        float4 w2 = Wv[(k0 + 2) * CG + cg];
        float4 w3 = Wv[(k0 + 3) * CG + cg];
        #pragma unroll
        for (int i = 0; i < RPT; ++i) {
            const float* lr = lds + (rt * RPT + i) * LD;
            float4 a = ((const float4*)lr)[k0 >> 2];
            acc[i].x += a.x * w0.x + a.y * w1.x + a.z * w2.x + a.w * w3.x;
            acc[i].y += a.x * w0.y + a.y * w1.y + a.z * w2.y + a.w * w3.y;
            acc[i].z += a.x * w0.z + a.y * w1.z + a.z * w2.z + a.w * w3.z;
            acc[i].w += a.x * w0.w + a.y * w1.w + a.z * w2.w + a.w * w3.w;
        }
    }

    #pragma unroll
    for (int i = 0; i < RPT; ++i) {
        int gr = row0 + rt * RPT + i;
        if (gr < NN) ((float4*)(out + (size_t)gr * 64))[cg] = acc[i];
    }
}

// ---------------- fp32 pull aggregation (layer 3, F=64) ----------------

__global__ __launch_bounds__(256) void agg_f32_kernel(const float* __restrict__ hin,
                                                      const int* __restrict__ row_ptr,
                                                      const int2* __restrict__ eg,
                                                      const float* __restrict__ bias,
                                                      float* __restrict__ out) {
    constexpr int GPL = 16;     // 64/4
    const int t = threadIdx.x;
    const int group = t / GPL;
    const int lane  = t % GPL;
    const int wid = blockIdx.x * 16 + group;
    if (wid >= NN) return;

    const int beg = row_ptr[wid];
    const int end = row_ptr[wid + 1];
    const float4* hv = (const float4*)hin;
    const int4* e4 = (const int4*)eg;
    float4 acc = make_float4(0.f, 0.f, 0.f, 0.f);

    for (int e = beg; e < end; e += 8) {
        int q = e >> 1;
        int4 p0 = e4[q + 0];
        int4 p1 = e4[q + 1];
        int4 p2 = e4[q + 2];
        int4 p3 = e4[q + 3];
        float4 v0 = hv[(size_t)p0.x * GPL + lane];
        float4 v1 = hv[(size_t)p0.z * GPL + lane];
        float4 v2 = hv[(size_t)p1.x * GPL + lane];
        float4 v3 = hv[(size_t)p1.z * GPL + lane];
        float4 v4 = hv[(size_t)p2.x * GPL + lane];
        float4 v5 = hv[(size_t)p2.z * GPL + lane];
        float4 v6 = hv[(size_t)p3.x * GPL + lane];
        float4 v7 = hv[(size_t)p3.z * GPL + lane];
        float w0 = __int_as_float(p0.y), w1 = __int_as_float(p0.w);
        float w2 = __int_as_float(p1.y), w3 = __int_as_float(p1.w);
        float w4 = __int_as_float(p2.y), w5 = __int_as_float(p2.w);
        float w6 = __int_as_float(p3.y), w7 = __int_as_float(p3.w);
        acc.x += w0*v0.x + w1*v1.x + w2*v2.x + w3*v3.x + w4*v4.x + w5*v5.x + w6*v6.x + w7*v7.x;
        acc.y += w0*v0.y + w1*v1.y + w2*v2.y + w3*v3.y + w4*v4.y + w5*v5.y + w6*v6.y + w7*v7.y;
        acc.z += w0*v0.z + w1*v1.z + w2*v2.z + w3*v3.z + w4*v4.z + w5*v5.z + w6*v6.z + w7*v7.z;
        acc.w += w0*v0.w + w1*v1.w + w2*v2.w + w3*v3.w + w4*v4.w + w5*v5.w + w6*v6.w + w7*v7.w;
    }

    float4 b = ((const float4*)bias)[lane];
    acc.x += b.x; acc.y += b.y; acc.z += b.z; acc.w += b.w;
    ((float4*)(out + (size_t)wid * 64))[lane] = acc;
}

// ---------------- launch ----------------

extern "C" void kernel_launch(void* const* d_in, const int* in_sizes, int n_in,
                              void* d_out, int out_size, void* d_ws, size_t ws_size,
                              hipStream_t stream) {
    const float* x  = (const float*)d_in[0];
    const int*   ei = (const int*)d_in[1];     // [2, NE], row0=src, row1=dst
    const float* W1 = (const float*)d_in[2];
    const float* b1 = (const float*)d_in[3];
    const float* W2 = (const float*)d_in[4];
    const float* b2 = (const float*)d_in[5];
    const float* W3 = (const float*)d_in[6];
    const float* b3 = (const float*)d_in[7];
    float* out = (float*)d_out;

    char* w = (char*)d_ws;
    int*   cnt     = (int*)  (w + 0x000000);    // N ints
    int*   row_ptr = (int*)  (w + 0x040000);    // N+1 ints
    int*   cursor  = (int*)  (w + 0x080000);    // N ints
    float* dinv    = (float*)(w + 0x0C0000);    // N floats
    int*   bsum    = (int*)  (w + 0x0F1000);    // NB ints
    int*   boff    = (int*)  (w + 0x0F2000);    // NB ints
    int2*  eg      = (int2*) (w + 0x100000);    // <=1,150,000 int2 (9.2MB)
    unsigned short* hb = (unsigned short*)(w + 0xA00000);   // bf16 N*128 (12.8MB)
    unsigned short* zb = (unsigned short*)(w + 0x1700000);  // bf16 N*128 (12.8MB)
    float* h3      = (float*)(w + 0x2400000);   // fp32 N*64 (12.8MB), ends ~49.4MB

    const int* src = ei;
    const int* dst = ei + NE;

    hipMemsetAsync(cnt, 0, NN * sizeof(int), stream);
    hist_kernel<<<(NE + 255) / 256, 256, 0, stream>>>(dst, cnt);
    scan1_kernel<<<NB, 256, 0, stream>>>(cnt, bsum);
    scan2_kernel<<<1, 256, 0, stream>>>(bsum, boff);
    scan3_kernel<<<NB, 256, 0, stream>>>(cnt, boff, row_ptr, dinv, eg, cursor);
    scatter_kernel<<<(NE + 255) / 256, 256, 0, stream>>>(src, dst, dinv, cursor, eg);

    // layer 1: h1 = x @ W1 (MFMA, fp32 A) -> bf16 hb ; z1 = agg(h1)+b1, relu -> bf16 zb
    mfma_gemm_kernel<true><<<(NN + 63) / 64, 256, 0, stream>>>(x, W1, hb);
    agg_bf16_kernel<true><<<(NN + 15) / 16, 256, 0, stream>>>(hb, row_ptr, eg, b1, zb);
    // layer 2: bf16 A
    mfma_gemm_kernel<false><<<(NN + 63) / 64, 256, 0, stream>>>(zb, W2, hb);
    agg_bf16_kernel<true><<<(NN + 15) / 16, 256, 0, stream>>>(hb, row_ptr, eg, b2, zb);
    // layer 3: fp32 compute, bf16 input; fp32 agg straight to out
    gemm3_kernel<<<(NN + 63) / 64, 256, 0, stream>>>(zb, W3, h3);
    agg_f32_kernel<<<(NN + 15) / 16, 256, 0, stream>>>(h3, row_ptr, eg, b3, out);
}

// Round 7
// 276.924 us; speedup vs baseline: 1.9486x; 1.1515x over previous
//
#include <hip/hip_runtime.h>
#include <math.h>

#define NN 50000
#define NE 800000
#define NB  ((NN + 255) / 256)   // 196 scan blocks

using bf8v = __attribute__((ext_vector_type(8))) short;   // 8 bf16 (4 VGPRs)
using f4v  = __attribute__((ext_vector_type(4))) float;   // 4 fp32 acc

__device__ inline unsigned short f2bf(float f) {          // RNE f32->bf16
    unsigned int u = __float_as_uint(f);
    u += 0x7FFFu + ((u >> 16) & 1u);
    return (unsigned short)(u >> 16);
}
__device__ inline float bflo(unsigned int d) { return __uint_as_float(d << 16); }
__device__ inline float bfhi(unsigned int d) { return __uint_as_float(d & 0xFFFF0000u); }

// ---------------- CSR build ----------------
// 4-way sharded histogram; atomic RETURNS rank -> placement pass is atomic-free.
// Rows padded to 8 edges with (col=0,w=0); edges packed int2{col, f32bits(w)}.

__global__ __launch_bounds__(256) void hist_rank_kernel(const int* __restrict__ dst,
                                                        int* __restrict__ cnt4,
                                                        int* __restrict__ rank) {
    int e = blockIdx.x * 256 + threadIdx.x;
    if (e < NE) {
        int d = dst[e];
        rank[e] = atomicAdd(&cnt4[(d << 2) | (e & 3)], 1);
    }
}

__global__ __launch_bounds__(256) void scan1_kernel(const int* __restrict__ cnt4,
                                                    int* __restrict__ bsum) {
    __shared__ int tmp[256];
    int t = threadIdx.x;
    int i = blockIdx.x * 256 + t;
    int v = 0;
    if (i < NN) {
        int4 c = ((const int4*)cnt4)[i];
        int deg = 1 + c.x + c.y + c.z + c.w;
        v = (deg + 7) & ~7;
    }
    tmp[t] = v;
    __syncthreads();
    #pragma unroll
    for (int s = 128; s > 0; s >>= 1) {
        if (t < s) tmp[t] += tmp[t + s];
        __syncthreads();
    }
    if (t == 0) bsum[blockIdx.x] = tmp[0];
}

__global__ __launch_bounds__(256) void scan2_kernel(const int* __restrict__ bsum,
                                                    int* __restrict__ boff) {
    __shared__ int tmp[256];
    int t = threadIdx.x;
    int v = (t < NB) ? bsum[t] : 0;
    tmp[t] = v;
    __syncthreads();
    #pragma unroll
    for (int s = 1; s < 256; s <<= 1) {
        int u = (t >= s) ? tmp[t - s] : 0;
        __syncthreads();
        tmp[t] += u;
        __syncthreads();
    }
    if (t < NB) boff[t] = tmp[t] - v;
}

// row_ptr (padded), dinv, self-loop, pad edges, per-shard bases.
__global__ __launch_bounds__(256) void scan3_kernel(const int* __restrict__ cnt4,
                                                    const int* __restrict__ boff,
                                                    int* __restrict__ row_ptr,
                                                    float* __restrict__ dinv,
                                                    int2* __restrict__ eg,
                                                    int4* __restrict__ shardbase) {
    __shared__ int tmp[256];
    int t = threadIdx.x;
    int i = blockIdx.x * 256 + t;
    int4 c = make_int4(0, 0, 0, 0);
    int deg = 0, vpad = 0;
    if (i < NN) {
        c = ((const int4*)cnt4)[i];
        deg = 1 + c.x + c.y + c.z + c.w;
        vpad = (deg + 7) & ~7;
    }
    tmp[t] = vpad;
    __syncthreads();
    #pragma unroll
    for (int s = 1; s < 256; s <<= 1) {
        int u = (t >= s) ? tmp[t - s] : 0;
        __syncthreads();
        tmp[t] += u;
        __syncthreads();
    }
    if (i < NN) {
        int rp = boff[blockIdx.x] + tmp[t] - vpad;
        row_ptr[i] = rp;
        float di = rsqrtf((float)deg);
        dinv[i] = di;
        int2 self; self.x = i; self.y = __float_as_int(di * di);
        eg[rp] = self;
        int4 sb;
        sb.x = rp + 1;
        sb.y = sb.x + c.x;
        sb.z = sb.y + c.y;
        sb.w = sb.z + c.z;
        shardbase[i] = sb;
        int2 pad; pad.x = 0; pad.y = 0;
        for (int p = rp + deg; p < rp + vpad; ++p) eg[p] = pad;
        if (i == NN - 1) row_ptr[NN] = rp + vpad;
    }
}

// atomic-free placement: p = shardbase[d][e&3] + rank[e]
__global__ __launch_bounds__(256) void place_kernel(const int* __restrict__ src,
                                                    const int* __restrict__ dst,
                                                    const float* __restrict__ dinv,
                                                    const int* __restrict__ rank,
                                                    const int* __restrict__ shardflat,
                                                    int2* __restrict__ eg) {
    int e = blockIdx.x * 256 + threadIdx.x;
    if (e < NE) {
        int s = src[e], d = dst[e];
        int p = shardflat[(d << 2) | (e & 3)] + rank[e];
        int2 pk; pk.x = s; pk.y = __float_as_int(dinv[s] * dinv[d]);
        eg[p] = pk;
    }
}

// ---------------- MFMA bf16 GEMM (layers 1-2): out_bf16[N x 128] = A[N x 128] @ W[128 x 128] ----

template <bool A_FP32>
__global__ __launch_bounds__(256) void mfma_gemm_kernel(const void* __restrict__ Ain,
                                                        const float* __restrict__ W,
                                                        unsigned short* __restrict__ out) {
    __shared__ unsigned short Wt[128 * 136];   // [n][k] bf16, padded
    __shared__ unsigned short Dt[64 * 136];    // [m][n] bf16, padded
    const int t = threadIdx.x;
    const int row0 = blockIdx.x * 64;

    {
        int n = t & 127;
        int kbase = (t >> 7) * 4;
        for (int kk = kbase; kk < 128; kk += 8) {
            float w0 = W[(kk + 0) * 128 + n];
            float w1 = W[(kk + 1) * 128 + n];
            float w2 = W[(kk + 2) * 128 + n];
            float w3 = W[(kk + 3) * 128 + n];
            unsigned int p0 = (unsigned int)f2bf(w0) | ((unsigned int)f2bf(w1) << 16);
            unsigned int p1 = (unsigned int)f2bf(w2) | ((unsigned int)f2bf(w3) << 16);
            *(unsigned int*)&Wt[n * 136 + kk]     = p0;
            *(unsigned int*)&Wt[n * 136 + kk + 2] = p1;
        }
    }
    __syncthreads();

    const int wave = t >> 6;
    const int lane = t & 63;
    const int m16  = lane & 15;
    const int quad = lane >> 4;
    const int arow = row0 + wave * 16 + m16;
    const int arowc = (arow < NN) ? arow : 0;

    f4v acc[8];
    #pragma unroll
    for (int i = 0; i < 8; ++i) acc[i] = (f4v)(0.0f);

    #pragma unroll
    for (int k0 = 0; k0 < 128; k0 += 32) {
        bf8v afrag;
        if (A_FP32) {
            const float* A = (const float*)Ain;
            const float4* ap = (const float4*)(A + (size_t)arowc * 128 + k0 + quad * 8);
            float4 a0 = ap[0], a1 = ap[1];
            afrag[0] = (short)f2bf(a0.x); afrag[1] = (short)f2bf(a0.y);
            afrag[2] = (short)f2bf(a0.z); afrag[3] = (short)f2bf(a0.w);
            afrag[4] = (short)f2bf(a1.x); afrag[5] = (short)f2bf(a1.y);
            afrag[6] = (short)f2bf(a1.z); afrag[7] = (short)f2bf(a1.w);
        } else {
            const unsigned short* A = (const unsigned short*)Ain;
            afrag = *(const bf8v*)(A + (size_t)arowc * 128 + k0 + quad * 8);
        }
        #pragma unroll
        for (int nt = 0; nt < 8; ++nt) {
            bf8v bfrag = *(const bf8v*)&Wt[(nt * 16 + m16) * 136 + k0 + quad * 8];
            acc[nt] = __builtin_amdgcn_mfma_f32_16x16x32_bf16(afrag, bfrag, acc[nt], 0, 0, 0);
        }
    }

    #pragma unroll
    for (int nt = 0; nt < 8; ++nt) {
        #pragma unroll
        for (int r = 0; r < 4; ++r) {
            Dt[(wave * 16 + quad * 4 + r) * 136 + nt * 16 + m16] = f2bf(acc[nt][r]);
        }
    }
    __syncthreads();

    {
        int r = t >> 2;
        int c = t & 3;
        int gr = row0 + r;
        if (gr < NN) {
            const uint4* s = (const uint4*)&Dt[r * 136] + c * 4;
            uint4* d = (uint4*)(out + (size_t)gr * 128) + c * 4;
            d[0] = s[0]; d[1] = s[1]; d[2] = s[2]; d[3] = s[3];
        }
    }
}

// ---------------- bf16 pull aggregation (layers 1-2) ----------------

template <bool RELU>
__global__ __launch_bounds__(256) void agg_bf16_kernel(const unsigned short* __restrict__ hin,
                                                       const int* __restrict__ row_ptr,
                                                       const int2* __restrict__ eg,
                                                       const float* __restrict__ bias,
                                                       unsigned short* __restrict__ outb) {
    const int t = threadIdx.x;
    const int group = t >> 4;
    const int lane  = t & 15;
    const int wid = blockIdx.x * 16 + group;
    if (wid >= NN) return;

    const int beg = row_ptr[wid];
    const int end = row_ptr[wid + 1];
    const uint4* hv = (const uint4*)hin;
    const int4* e4 = (const int4*)eg;

    float acc[8] = {0.f, 0.f, 0.f, 0.f, 0.f, 0.f, 0.f, 0.f};

    for (int e = beg; e < end; e += 8) {
        int q = e >> 1;
        int4 p0 = e4[q + 0];
        int4 p1 = e4[q + 1];
        int4 p2 = e4[q + 2];
        int4 p3 = e4[q + 3];
        uint4 g0 = hv[(size_t)p0.x * 16 + lane];
        uint4 g1 = hv[(size_t)p0.z * 16 + lane];
        uint4 g2 = hv[(size_t)p1.x * 16 + lane];
        uint4 g3 = hv[(size_t)p1.z * 16 + lane];
        uint4 g4 = hv[(size_t)p2.x * 16 + lane];
        uint4 g5 = hv[(size_t)p2.z * 16 + lane];
        uint4 g6 = hv[(size_t)p3.x * 16 + lane];
        uint4 g7 = hv[(size_t)p3.z * 16 + lane];
        float w0 = __int_as_float(p0.y), w1 = __int_as_float(p0.w);
        float w2 = __int_as_float(p1.y), w3 = __int_as_float(p1.w);
        float w4 = __int_as_float(p2.y), w5 = __int_as_float(p2.w);
        float w6 = __int_as_float(p3.y), w7 = __int_as_float(p3.w);
        #define ACCUM(G, W_) \
            acc[0] += W_ * bflo(G.x); acc[1] += W_ * bfhi(G.x); \
            acc[2] += W_ * bflo(G.y); acc[3] += W_ * bfhi(G.y); \
            acc[4] += W_ * bflo(G.z); acc[5] += W_ * bfhi(G.z); \
            acc[6] += W_ * bflo(G.w); acc[7] += W_ * bfhi(G.w);
        ACCUM(g0, w0) ACCUM(g1, w1) ACCUM(g2, w2) ACCUM(g3, w3)
        ACCUM(g4, w4) ACCUM(g5, w5) ACCUM(g6, w6) ACCUM(g7, w7)
        #undef ACCUM
    }

    const float4* bp = (const float4*)bias;
    float4 b0 = bp[lane * 2], b1 = bp[lane * 2 + 1];
    acc[0] += b0.x; acc[1] += b0.y; acc[2] += b0.z; acc[3] += b0.w;
    acc[4] += b1.x; acc[5] += b1.y; acc[6] += b1.z; acc[7] += b1.w;
    if (RELU) {
        #pragma unroll
        for (int j = 0; j < 8; ++j) acc[j] = fmaxf(acc[j], 0.f);
    }
    uint4 o;
    o.x = (unsigned int)f2bf(acc[0]) | ((unsigned int)f2bf(acc[1]) << 16);
    o.y = (unsigned int)f2bf(acc[2]) | ((unsigned int)f2bf(acc[3]) << 16);
    o.z = (unsigned int)f2bf(acc[4]) | ((unsigned int)f2bf(acc[5]) << 16);
    o.w = (unsigned int)f2bf(acc[6]) | ((unsigned int)f2bf(acc[7]) << 16);
    ((uint4*)(outb + (size_t)wid * 128))[lane] = o;
}

// ---------------- layer-3 GEMM (fp32 compute, bf16 in, bf16 out): h3 = z2 @ W3 ----------------

__global__ __launch_bounds__(256) void gemm3_kernel(const unsigned short* __restrict__ Ab,
                                                    const float* __restrict__ W,
                                                    unsigned short* __restrict__ outh) {
    constexpr int CG = 16;
    constexpr int RPT = 4;
    constexpr int ROWS = 64;
    constexpr int LD = 132;
    __shared__ float lds[ROWS * LD];
    const int t = threadIdx.x;
    const int row0 = blockIdx.x * ROWS;

    #pragma unroll
    for (int j = 0; j < ROWS / 8; ++j) {
        int idx4 = j * 256 + t;
        int r = idx4 >> 5, c4 = idx4 & 31;
        int gr = row0 + r;
        uint2 u = make_uint2(0u, 0u);
        if (gr < NN) u = ((const uint2*)(Ab + (size_t)gr * 128))[c4];
        float4 v;
        v.x = bflo(u.x); v.y = bfhi(u.x); v.z = bflo(u.y); v.w = bfhi(u.y);
        ((float4*)(lds + r * LD))[c4] = v;
    }
    __syncthreads();

    const int cg = t % CG;
    const int rt = t / CG;
    const float4* Wv = (const float4*)W;
    float4 acc[RPT];
    #pragma unroll
    for (int i = 0; i < RPT; ++i) acc[i] = make_float4(0.f, 0.f, 0.f, 0.f);

    for (int k0 = 0; k0 < 128; k0 += 4) {
        float4 w0 = Wv[(k0 + 0) * CG + cg];
        float4 w1 = Wv[(k0 + 1) * CG + cg];
        float4 w2 = Wv[(k0 + 2) * CG + cg];
        float4 w3 = Wv[(k0 + 3) * CG + cg];
        #pragma unroll
        for (int i = 0; i < RPT; ++i) {
            const float* lr = lds + (rt * RPT + i) * LD;
            float4 a = ((const float4*)lr)[k0 >> 2];
            acc[i].x += a.x * w0.x + a.y * w1.x + a.z * w2.x + a.w * w3.x;
            acc[i].y += a.x * w0.y + a.y * w1.y + a.z * w2.y + a.w * w3.y;
            acc[i].z += a.x * w0.z + a.y * w1.z + a.z * w2.z + a.w * w3.z;
            acc[i].w += a.x * w0.w + a.y * w1.w + a.z * w2.w + a.w * w3.w;
        }
    }

    #pragma unroll
    for (int i = 0; i < RPT; ++i) {
        int gr = row0 + rt * RPT + i;
        if (gr < NN) {
            uint2 o;
            o.x = (unsigned int)f2bf(acc[i].x) | ((unsigned int)f2bf(acc[i].y) << 16);
            o.y = (unsigned int)f2bf(acc[i].z) | ((unsigned int)f2bf(acc[i].w) << 16);
            ((uint2*)(outh + (size_t)gr * 64))[cg] = o;
        }
    }
}

// ---------------- layer-3 aggregation: bf16 gather (128B rows) -> fp32 out ----------------
// 8 lanes/group (uint4 = 8 bf16 feats), 32 groups/block, 8-edge unroll.

__global__ __launch_bounds__(256) void agg3_kernel(const unsigned short* __restrict__ hin,
                                                   const int* __restrict__ row_ptr,
                                                   const int2* __restrict__ eg,
                                                   const float* __restrict__ bias,
                                                   float* __restrict__ out) {
    const int t = threadIdx.x;
    const int group = t >> 3;
    const int lane  = t & 7;
    const int wid = blockIdx.x * 32 + group;
    if (wid >= NN) return;

    const int beg = row_ptr[wid];
    const int end = row_ptr[wid + 1];
    const uint4* hv = (const uint4*)hin;      // 8 uint4 per 64-feat bf16 row
    const int4* e4 = (const int4*)eg;

    float acc[8] = {0.f, 0.f, 0.f, 0.f, 0.f, 0.f, 0.f, 0.f};

    for (int e = beg; e < end; e += 8) {
        int q = e >> 1;
        int4 p0 = e4[q + 0];
        int4 p1 = e4[q + 1];
        int4 p2 = e4[q + 2];
        int4 p3 = e4[q + 3];
        uint4 g0 = hv[(size_t)p0.x * 8 + lane];
        uint4 g1 = hv[(size_t)p0.z * 8 + lane];
        uint4 g2 = hv[(size_t)p1.x * 8 + lane];
        uint4 g3 = hv[(size_t)p1.z * 8 + lane];
        uint4 g4 = hv[(size_t)p2.x * 8 + lane];
        uint4 g5 = hv[(size_t)p2.z * 8 + lane];
        uint4 g6 = hv[(size_t)p3.x * 8 + lane];
        uint4 g7 = hv[(size_t)p3.z * 8 + lane];
        float w0 = __int_as_float(p0.y), w1 = __int_as_float(p0.w);
        float w2 = __int_as_float(p1.y), w3 = __int_as_float(p1.w);
        float w4 = __int_as_float(p2.y), w5 = __int_as_float(p2.w);
        float w6 = __int_as_float(p3.y), w7 = __int_as_float(p3.w);
        #define ACCUM(G, W_) \
            acc[0] += W_ * bflo(G.x); acc[1] += W_ * bfhi(G.x); \
            acc[2] += W_ * bflo(G.y); acc[3] += W_ * bfhi(G.y); \
            acc[4] += W_ * bflo(G.z); acc[5] += W_ * bfhi(G.z); \
            acc[6] += W_ * bflo(G.w); acc[7] += W_ * bfhi(G.w);
        ACCUM(g0, w0) ACCUM(g1, w1) ACCUM(g2, w2) ACCUM(g3, w3)
        ACCUM(g4, w4) ACCUM(g5, w5) ACCUM(g6, w6) ACCUM(g7, w7)
        #undef ACCUM
    }

    const float4* bp = (const float4*)bias;
    float4 b0 = bp[lane * 2], b1 = bp[lane * 2 + 1];
    acc[0] += b0.x; acc[1] += b0.y; acc[2] += b0.z; acc[3] += b0.w;
    acc[4] += b1.x; acc[5] += b1.y; acc[6] += b1.z; acc[7] += b1.w;

    float4 o0 = make_float4(acc[0], acc[1], acc[2], acc[3]);
    float4 o1 = make_float4(acc[4], acc[5], acc[6], acc[7]);
    ((float4*)(out + (size_t)wid * 64))[lane * 2]     = o0;
    ((float4*)(out + (size_t)wid * 64))[lane * 2 + 1] = o1;
}

// ---------------- launch ----------------

extern "C" void kernel_launch(void* const* d_in, const int* in_sizes, int n_in,
                              void* d_out, int out_size, void* d_ws, size_t ws_size,
                              hipStream_t stream) {
    const float* x  = (const float*)d_in[0];
    const int*   ei = (const int*)d_in[1];     // [2, NE], row0=src, row1=dst
    const float* W1 = (const float*)d_in[2];
    const float* b1 = (const float*)d_in[3];
    const float* W2 = (const float*)d_in[4];
    const float* b2 = (const float*)d_in[5];
    const float* W3 = (const float*)d_in[6];
    const float* b3 = (const float*)d_in[7];
    float* out = (float*)d_out;

    // Workspace map (verified non-overlapping; sizes in bytes):
    //   cnt4      0x0000000  200000*4 = 0x0C3500  -> ends 0x0C3500
    //   row_ptr   0x0100000  200004   = 0x030D44  -> ends 0x130D44
    //   shardbase 0x0140000  800000   = 0x0C3500  -> ends 0x203500
    //   dinv      0x0210000  200000   = 0x030D40  -> ends 0x240D40
    //   bsum      0x0250000  784
    //   boff      0x0251000  784
    //   rank      0x0260000  3200000  = 0x30D400  -> ends 0x56D400
    //   eg        0x0580000  <=1.2M int2 = 0x927C00 -> ends 0xEA7C00
    //   hb        0x1000000  12.8MB   = 0xC35000  -> ends 0x1C35000
    //   zb        0x1D00000  12.8MB              -> ends 0x2935000
    //   h3b       0x2A00000  6.4MB    = 0x61A800  -> ends 0x301A800 (~50.4MB)
    char* w = (char*)d_ws;
    int*   cnt4      = (int*)  (w + 0x0000000);
    int*   row_ptr   = (int*)  (w + 0x0100000);
    int4*  shardbase = (int4*) (w + 0x0140000);
    float* dinv      = (float*)(w + 0x0210000);
    int*   bsum      = (int*)  (w + 0x0250000);
    int*   boff      = (int*)  (w + 0x0251000);
    int*   rank      = (int*)  (w + 0x0260000);
    int2*  eg        = (int2*) (w + 0x0580000);
    unsigned short* hb  = (unsigned short*)(w + 0x1000000);
    unsigned short* zb  = (unsigned short*)(w + 0x1D00000);
    unsigned short* h3b = (unsigned short*)(w + 0x2A00000);

    const int* src = ei;
    const int* dst = ei + NE;

    hipMemsetAsync(cnt4, 0, NN * 4 * sizeof(int), stream);
    hist_rank_kernel<<<(NE + 255) / 256, 256, 0, stream>>>(dst, cnt4, rank);
    scan1_kernel<<<NB, 256, 0, stream>>>(cnt4, bsum);
    scan2_kernel<<<1, 256, 0, stream>>>(bsum, boff);
    scan3_kernel<<<NB, 256, 0, stream>>>(cnt4, boff, row_ptr, dinv, eg, shardbase);
    place_kernel<<<(NE + 255) / 256, 256, 0, stream>>>(src, dst, dinv, rank,
                                                       (const int*)shardbase, eg);

    // layer 1: h1 = x @ W1 (MFMA, fp32 A) -> bf16 hb ; z1 = agg(h1)+b1, relu -> bf16 zb
    mfma_gemm_kernel<true><<<(NN + 63) / 64, 256, 0, stream>>>(x, W1, hb);
    agg_bf16_kernel<true><<<(NN + 15) / 16, 256, 0, stream>>>(hb, row_ptr, eg, b1, zb);
    // layer 2
    mfma_gemm_kernel<false><<<(NN + 63) / 64, 256, 0, stream>>>(zb, W2, hb);
    agg_bf16_kernel<true><<<(NN + 15) / 16, 256, 0, stream>>>(hb, row_ptr, eg, b2, zb);
    // layer 3: fp32 compute, bf16 h3; fp32 agg straight to out
    gemm3_kernel<<<(NN + 63) / 64, 256, 0, stream>>>(zb, W3, h3b);
    agg3_kernel<<<(NN + 31) / 32, 256, 0, stream>>>(h3b, row_ptr, eg, b3, out);
}